// Round 9
// baseline (6151.200 us; speedup 1.0000x reference)
//
#include <hip/hip_runtime.h>

// ---------------------------------------------------------------------------
// TextClassification: embedding -> LSTM(2048 steps) -> linear head
// V=50257 D=256 H=256 O=10 L=2048 N=64
//
// Structure (2 chunks of 1024 steps; gates chunk = 134 MB of 256 MiB ws):
//   Phase A: fp16 MFMA GEMM gates[m][p] = emb[x[m]].Wx[p] + (bx+bh)[p]
//   Phase B: 64 blocks (1 CU per chain), 512 threads. Wave w owns weight
//     rows [128w,128w+128); thread owns 2 full K=256 rows. Weights served
//     from 3 parallel pipes per step:
//       - kc 0-5   : 48 regs/thread resident (96 KB/CU register file)
//       - kc 6-11  : 96 KB LDS cache
//       - kc 12-31 : 320 KB streamed from L2 via a phase-stable 5-slot
//         register ring (reissue-on-consume, ~1-step lead, loads stay in
//         flight ACROSS raw s_barriers -- no vmcnt drain)
//     Pre-acts combined via 4 KB LDS exchange; h published in LDS.
//   Phase C: folded into last chunk tail.
// Round-8 lesson: cross-CU LLC sync costs >=1500-3000 cyc/step -> stay
// single-CU; round-3 lesson: __syncthreads() drains vmcnt -> raw barriers.
// ---------------------------------------------------------------------------

using half_t  = _Float16;
using half2_t = __attribute__((ext_vector_type(2))) _Float16;
using half8_t = __attribute__((ext_vector_type(8))) _Float16;
using f32x4   = __attribute__((ext_vector_type(4))) float;

#define L_SEQ   2048
#define CHUNK_L 1024
#define NB      64
#define DIM     256
#define P4      1024                 // 4 gates * H
#define CM      (CHUNK_L * NB)       // 65536 rows per chunk

// workspace layout (bytes)
#define OFF_GATES 0ull
#define SZ_GATES  ((unsigned long long)CM * P4 * 2)        // 134217728
#define OFF_EMBH  (OFF_GATES + SZ_GATES)
#define SZ_EMBH   (50257ull * 256 * 2)                     // 25731584
#define OFF_WX    (OFF_EMBH + SZ_EMBH)
#define SZ_WX     (1024ull * 256 * 2)
#define OFF_WH    (OFF_WX + SZ_WX)
#define SZ_WH     (1024ull * 256 * 2)
#define OFF_B4    (OFF_WH + SZ_WH)
#define SZ_B4     (1024ull * 4)
#define OFF_ST    (OFF_B4 + SZ_B4)
#define SZ_ST     (2ull * NB * DIM * 4)                    // h,c f32 state
#define WS_NEED   (OFF_ST + SZ_ST)                         // ~161.1 MB

// ---------------- helpers ----------------
__device__ __forceinline__ float sigm(float x) {
  x = fminf(fmaxf(x, -30.f), 30.f);
  return 1.f / (1.f + __expf(-x));
}
__device__ __forceinline__ float tanh_(float x) {
  x = fminf(fmaxf(x, -15.f), 15.f);
  float t = __expf(2.f * x);
  return (t - 1.f) / (t + 1.f);
}
__device__ __forceinline__ float dot8(half8_t w, half8_t h, float acc) {
  acc = __builtin_amdgcn_fdot2((half2_t)__builtin_shufflevector(w, w, 0, 1),
                               (half2_t)__builtin_shufflevector(h, h, 0, 1), acc, false);
  acc = __builtin_amdgcn_fdot2((half2_t)__builtin_shufflevector(w, w, 2, 3),
                               (half2_t)__builtin_shufflevector(h, h, 2, 3), acc, false);
  acc = __builtin_amdgcn_fdot2((half2_t)__builtin_shufflevector(w, w, 4, 5),
                               (half2_t)__builtin_shufflevector(h, h, 4, 5), acc, false);
  acc = __builtin_amdgcn_fdot2((half2_t)__builtin_shufflevector(w, w, 6, 7),
                               (half2_t)__builtin_shufflevector(h, h, 6, 7), acc, false);
  return acc;
}

// raw barrier: order LDS only; leave global loads in flight (no vmcnt drain)
#define BAR() do {                                        \
    asm volatile("s_waitcnt lgkmcnt(0)" ::: "memory");    \
    __builtin_amdgcn_s_barrier();                         \
    asm volatile("" ::: "memory");                        \
  } while (0)

// ---------------- kernels ----------------
__global__ void ws_too_small_kernel(float* out, float sz) {
  if (threadIdx.x == 0 && blockIdx.x == 0) out[0] = sz;
}

__global__ void cvt_emb_kernel(const float* __restrict__ src, half_t* __restrict__ dst,
                               int total8) {
  int i = blockIdx.x * blockDim.x + threadIdx.x;
  if (i >= total8) return;
  const float4* s = (const float4*)src + (size_t)i * 2;
  float4 a = s[0], b = s[1];
  half8_t o;
  o[0] = (half_t)a.x; o[1] = (half_t)a.y; o[2] = (half_t)a.z; o[3] = (half_t)a.w;
  o[4] = (half_t)b.x; o[5] = (half_t)b.y; o[6] = (half_t)b.z; o[7] = (half_t)b.w;
  *((half8_t*)dst + i) = o;
}

// Wx4h[p][k] row-major fp16; Wh4c[(k>>3)][p][k&7] (16B chunk per (kc,p));
// b4 = bx + bh
__global__ void pack_w_kernel(const float* __restrict__ Wii, const float* __restrict__ Whi,
                              const float* __restrict__ Wif, const float* __restrict__ Whf,
                              const float* __restrict__ Wig, const float* __restrict__ Whg,
                              const float* __restrict__ Wio, const float* __restrict__ Who,
                              const float* __restrict__ bii, const float* __restrict__ bhi,
                              const float* __restrict__ bif, const float* __restrict__ bhf,
                              const float* __restrict__ big_, const float* __restrict__ bhg,
                              const float* __restrict__ bio, const float* __restrict__ bho,
                              half_t* __restrict__ Wx4h, half_t* __restrict__ Wh4c,
                              float* __restrict__ b4) {
  int p = blockIdx.x;   // 0..1023
  int k = threadIdx.x;  // 0..255
  int g = p >> 8, h = p & 255;
  const float* Wx = g == 0 ? Wii : g == 1 ? Wif : g == 2 ? Wig : Wio;
  const float* Wh = g == 0 ? Whi : g == 1 ? Whf : g == 2 ? Whg : Who;
  Wx4h[(size_t)p * DIM + k] = (half_t)Wx[h * DIM + k];
  Wh4c[((size_t)(k >> 3) * P4 + p) * 8 + (k & 7)] = (half_t)Wh[h * DIM + k];
  if (k == 0) {
    const float* bx = g == 0 ? bii : g == 1 ? bif : g == 2 ? big_ : bio;
    const float* bh = g == 0 ? bhi : g == 1 ? bhf : g == 2 ? bhg : bho;
    b4[p] = bx[h] + bh[h];
  }
}

// Phase A GEMM (unchanged; 128x128 tile, mfma_f32_16x16x32_f16)
#define BK   32
#define LSTR 40
__global__ __launch_bounds__(256) void gemm_gates_kernel(
    const half_t* __restrict__ embh, const int* __restrict__ xc,
    const half_t* __restrict__ Wx4h, const float* __restrict__ b4,
    half_t* __restrict__ gates) {
  __shared__ __align__(16) half_t As[128 * LSTR];
  __shared__ __align__(16) half_t Ws[128 * LSTR];
  const int tid  = threadIdx.x;
  const int lane = tid & 63;
  const int wave = tid >> 6;
  const int wm = wave >> 1, wn = wave & 1;
  const int M0 = blockIdx.x * 128;
  const int P0 = blockIdx.y * 128;
  const int r0 = tid >> 2, s0 = tid & 3;

  const size_t arow0 = (size_t)xc[M0 + r0] * DIM;
  const size_t arow1 = (size_t)xc[M0 + 64 + r0] * DIM;
  const size_t wrow0 = (size_t)(P0 + r0) * DIM;
  const size_t wrow1 = (size_t)(P0 + 64 + r0) * DIM;

  f32x4 acc[4][4] = {};
  const int fr = lane & 15;
  const int kq = lane >> 4;

  for (int kt = 0; kt < 8; ++kt) {
    const int k0 = kt * BK;
    half8_t a0 = *(const half8_t*)(embh + arow0 + k0 + s0 * 8);
    half8_t a1 = *(const half8_t*)(embh + arow1 + k0 + s0 * 8);
    half8_t w0 = *(const half8_t*)(Wx4h + wrow0 + k0 + s0 * 8);
    half8_t w1 = *(const half8_t*)(Wx4h + wrow1 + k0 + s0 * 8);
    __syncthreads();
    *(half8_t*)(As + r0 * LSTR + s0 * 8)        = a0;
    *(half8_t*)(As + (r0 + 64) * LSTR + s0 * 8) = a1;
    *(half8_t*)(Ws + r0 * LSTR + s0 * 8)        = w0;
    *(half8_t*)(Ws + (r0 + 64) * LSTR + s0 * 8) = w1;
    __syncthreads();
    half8_t af[4], bf[4];
#pragma unroll
    for (int mi = 0; mi < 4; ++mi)
      af[mi] = *(const half8_t*)(As + (wm * 64 + mi * 16 + fr) * LSTR + kq * 8);
#pragma unroll
    for (int ni = 0; ni < 4; ++ni)
      bf[ni] = *(const half8_t*)(Ws + (wn * 64 + ni * 16 + fr) * LSTR + kq * 8);
#pragma unroll
    for (int mi = 0; mi < 4; ++mi)
#pragma unroll
      for (int ni = 0; ni < 4; ++ni)
        acc[mi][ni] = __builtin_amdgcn_mfma_f32_16x16x32_f16(af[mi], bf[ni], acc[mi][ni], 0, 0, 0);
  }
  const int rbase = (lane >> 4) * 4;
#pragma unroll
  for (int ni = 0; ni < 4; ++ni) {
    const int p = P0 + wn * 64 + ni * 16 + fr;
    const float bias = b4[p];
#pragma unroll
    for (int mi = 0; mi < 4; ++mi) {
      const int m = M0 + wm * 64 + mi * 16 + rbase;
#pragma unroll
      for (int r = 0; r < 4; ++r)
        gates[(size_t)(m + r) * P4 + p] = (half_t)(acc[mi][ni][r] + bias);
    }
  }
}

// ---- weight-tier macros ----
#define DECLW(i) half8_t WA##i, WB##i;
#define LOADW(i) WA##i = W28[(i) * P4 + pA]; WB##i = W28[(i) * P4 + pB];
#define PINW(i)  asm volatile("" : "+v"(WA##i), "+v"(WB##i));
#define DOTA(i)  { const half8_t hh = hp[i]; \
                   aA = dot8(WA##i, hh, aA); aB = dot8(WB##i, hh, aB); }
#define DOTL(s)  { const half8_t hh = hp[6 + (s)]; \
                   aA = dot8(*(const half8_t*)wlds[s][pA], hh, aA); \
                   aB = dot8(*(const half8_t*)wlds[s][pB], hh, aB); }
// consume stream slot, immediately reissue it for chunk cn (next use ~1 step
// or >=5 chunk-periods away -> L2 latency hidden)
#define DOTS(idx, sl, cn) { const half8_t hh = hp[12 + (idx)]; \
                   aA = dot8(sA##sl, hh, aA); aB = dot8(sB##sl, hh, aB); \
                   sA##sl = W28[(cn) * P4 + pA]; sB##sl = W28[(cn) * P4 + pB]; }

// Phase B: 64 blocks (1 chain each), 512 threads. Wave w owns rows
// [128w,128w+128); thread: rows pA=128w+lane, pB=pA+64, full K=256.
__global__ __launch_bounds__(512)
void lstm_kernel(const half_t* __restrict__ gates, const half_t* __restrict__ Wh4c,
                 const float* __restrict__ Wout, const float* __restrict__ bout,
                 float* __restrict__ out, float* __restrict__ state,
                 int first, int last) {
  const int n    = blockIdx.x;
  const int tid  = threadIdx.x;
  const int w    = tid >> 6;
  const int lane = tid & 63;
  const int pA   = (w << 7) + lane;
  const int pB   = pA + 64;

  __shared__ __align__(16) half_t wlds[6][P4][8];  // 96 KB: kc 6..11
  __shared__ __align__(16) half_t hbuf[2][DIM];    // 1 KB
  __shared__ float pre[P4];                        // 4 KB pre-act exchange

  const half8_t* W28 = (const half8_t*)Wh4c;

  // LDS weight cache fill (kc 6..11)
  for (int i = tid; i < 6 * P4; i += 512) {
    const int s = i >> 10, pp = i & 1023;
    *(half8_t*)wlds[s][pp] = W28[(6 + s) * P4 + pp];
  }
  // register-resident tier (kc 0..5): 12 half8 = 48 regs
  DECLW(0) DECLW(1) DECLW(2) DECLW(3) DECLW(4) DECLW(5)
  LOADW(0) LOADW(1) LOADW(2) LOADW(3) LOADW(4) LOADW(5)
  PINW(0) PINW(1) PINW(2) PINW(3) PINW(4) PINW(5)
  // stream ring prime: slots 0..4 <- kc 12..16
  half8_t sA0 = W28[12 * P4 + pA], sB0 = W28[12 * P4 + pB];
  half8_t sA1 = W28[13 * P4 + pA], sB1 = W28[13 * P4 + pB];
  half8_t sA2 = W28[14 * P4 + pA], sB2 = W28[14 * P4 + pB];
  half8_t sA3 = W28[15 * P4 + pA], sB3 = W28[15 * P4 + pB];
  half8_t sA4 = W28[16 * P4 + pA], sB4 = W28[16 * P4 + pB];

  const half_t* gj = gates + (size_t)n * P4 + (tid & 255);
  float cc = 0.f;
  float g0f = 0.f, g1f = 0.f, g2f = 0.f, g3f = 0.f;
  if (tid < 256) {
    float h0 = 0.f;
    if (!first) { h0 = state[n * DIM + tid]; cc = state[NB * DIM + n * DIM + tid]; }
    hbuf[0][tid] = (half_t)h0;
    g0f = (float)gj[0];   g1f = (float)gj[256];
    g2f = (float)gj[512]; g3f = (float)gj[768];
  }
  __syncthreads();

  int par = 0;
#pragma unroll 1
  for (int l = 0; l < CHUNK_L; ++l) {
    const half8_t* hp = (const half8_t*)hbuf[par];
    float aA = 0.f, aB = 0.f;
    // next-step gate prefetch (VMEM, in flight across the whole step)
    half_t ng0 = (half_t)0.f, ng1 = ng0, ng2 = ng0, ng3 = ng0;
    if (tid < 256) {
      const half_t* gp2 = gj + (size_t)(l + 1) * (NB * P4);  // last read lands in embh: harmless
      ng0 = gp2[0]; ng1 = gp2[256]; ng2 = gp2[512]; ng3 = gp2[768];
    }
    // register tier kc 0-5 (no memory)
    DOTA(0) DOTA(1) DOTA(2) DOTA(3) DOTA(4) DOTA(5)
    // interleave: stream (primed >=1 step ago) + LDS tier
    DOTS(0, 0, 17)  DOTL(0)
    DOTS(1, 1, 18)  DOTL(1)
    DOTS(2, 2, 19)  DOTL(2)
    DOTS(3, 3, 20)  DOTL(3)
    DOTS(4, 4, 21)  DOTL(4)
    DOTS(5, 0, 22)  DOTL(5)
    DOTS(6, 1, 23)
    DOTS(7, 2, 24)
    DOTS(8, 3, 25)
    DOTS(9, 4, 26)
    DOTS(10, 0, 27)
    DOTS(11, 1, 28)
    DOTS(12, 2, 29)
    DOTS(13, 3, 30)
    DOTS(14, 4, 31)
    DOTS(15, 0, 12)   // wrap: reload kc 12..16 for NEXT step
    DOTS(16, 1, 13)
    DOTS(17, 2, 14)
    DOTS(18, 3, 15)
    DOTS(19, 4, 16)
    pre[pA] = aA;
    pre[pB] = aB;
    BAR();                         // pre-acts visible; stream loads stay in flight
    if (tid < 256) {
      const float ai  = pre[tid]       + g0f;
      const float af_ = pre[256 + tid] + g1f;
      const float ag  = pre[512 + tid] + g2f;
      const float ao  = pre[768 + tid] + g3f;
      cc = sigm(af_) * cc + sigm(ai) * tanh_(ag);
      const float hh = sigm(ao) * tanh_(cc);
      hbuf[par ^ 1][tid] = (half_t)hh;
      g0f = (float)ng0; g1f = (float)ng1; g2f = (float)ng2; g3f = (float)ng3;
    }
    BAR();                         // h published
    par ^= 1;
  }
  __syncthreads();
  // CHUNK_L even -> final h in hbuf[0]
  if (!last && tid < 256) {
    state[n * DIM + tid] = (float)hbuf[0][tid];
    state[NB * DIM + n * DIM + tid] = cc;
  }
  if (last && tid < 10) {
    float s = bout[tid];
    const float* wrow = Wout + tid * DIM;
#pragma unroll 4
    for (int k = 0; k < DIM; ++k) s += (float)hbuf[0][k] * wrow[k];
    out[n * 10 + tid] = s;
  }
}

// ---------------- launch ----------------
extern "C" void kernel_launch(void* const* d_in, const int* in_sizes, int n_in,
                              void* d_out, int out_size, void* d_ws, size_t ws_size,
                              hipStream_t stream) {
  const int*   x    = (const int*)d_in[0];
  const float* emb  = (const float*)d_in[1];
  const float* Wii  = (const float*)d_in[2];  const float* bii = (const float*)d_in[3];
  const float* Whi  = (const float*)d_in[4];  const float* bhi = (const float*)d_in[5];
  const float* Wif  = (const float*)d_in[6];  const float* bif = (const float*)d_in[7];
  const float* Whf  = (const float*)d_in[8];  const float* bhf = (const float*)d_in[9];
  const float* Wig  = (const float*)d_in[10]; const float* big_ = (const float*)d_in[11];
  const float* Whg  = (const float*)d_in[12]; const float* bhg = (const float*)d_in[13];
  const float* Wio  = (const float*)d_in[14]; const float* bio = (const float*)d_in[15];
  const float* Who  = (const float*)d_in[16]; const float* bho = (const float*)d_in[17];
  const float* Wout = (const float*)d_in[18]; const float* bout = (const float*)d_in[19];
  float* out = (float*)d_out;

  if (ws_size < WS_NEED) {  // fail loudly but safely: absmax will show ws_size
    hipLaunchKernelGGL(ws_too_small_kernel, dim3(1), dim3(64), 0, stream, out, (float)ws_size);
    return;
  }
  char* ws = (char*)d_ws;
  half_t* gates = (half_t*)(ws + OFF_GATES);
  half_t* embh  = (half_t*)(ws + OFF_EMBH);
  half_t* Wx4h  = (half_t*)(ws + OFF_WX);
  half_t* Wh4c  = (half_t*)(ws + OFF_WH);
  float*  b4    = (float*)(ws + OFF_B4);
  float*  state = (float*)(ws + OFF_ST);

  const int total8 = 50257 * 32;  // V*D/8
  hipLaunchKernelGGL(cvt_emb_kernel, dim3((total8 + 255) / 256), dim3(256), 0, stream,
                     emb, embh, total8);
  hipLaunchKernelGGL(pack_w_kernel, dim3(1024), dim3(256), 0, stream,
                     Wii, Whi, Wif, Whf, Wig, Whg, Wio, Who,
                     bii, bhi, bif, bhf, big_, bhg, bio, bho,
                     Wx4h, Wh4c, b4);
  // chunk 0: steps [0, 1024)
  hipLaunchKernelGGL(gemm_gates_kernel, dim3(CM / 128, P4 / 128), dim3(256), 0, stream,
                     embh, x, Wx4h, b4, gates);
  hipLaunchKernelGGL(lstm_kernel, dim3(NB), dim3(512), 0, stream,
                     gates, Wh4c, Wout, bout, out, state, 1, 0);
  // chunk 1: steps [1024, 2048)
  hipLaunchKernelGGL(gemm_gates_kernel, dim3(CM / 128, P4 / 128), dim3(256), 0, stream,
                     embh, x + (size_t)CHUNK_L * NB, Wx4h, b4, gates);
  hipLaunchKernelGGL(lstm_kernel, dim3(NB), dim3(512), 0, stream,
                     gates, Wh4c, Wout, bout, out, state, 0, 1);
}

// Round 10
// 4567.040 us; speedup vs baseline: 1.3469x; 1.3469x over previous
//
#include <hip/hip_runtime.h>

// ---------------------------------------------------------------------------
// TextClassification: embedding -> LSTM(2048 steps) -> linear head
// V=50257 D=256 H=256 O=10 L=2048 N=64
//
// 2 chunks of 1024 steps (gates chunk = 134 MB of the 256 MiB ws):
//   Phase A: fp16 MFMA GEMM gates[m][p] = emb[x[m]].Wx[p] + (bx+bh)[p]
//   Phase B: 64 blocks (1 CU per chain), 512 threads, thread=(j,kh):
//     j=unit 0..255 (4 gate rows), kh=K-half. Per-thread 16 kc chunks:
//       kc 0-3  : 16 half8 resident in VGPRs (64 regs; 128 KB/CU)
//       kc 4-7  : 128 KB LDS cache
//       kc 8-15 : streamed from L2 via 8-slot register ring, reissue-on-
//                 consume, interleaved with LDS/resident groups so the
//                 reuse distance covers L2 latency.
//     Barriers are raw s_barrier + lgkmcnt(0) with NO memory clobber
//     (round-9 lesson: asm "memory" clobber makes the waitcnt pass drain
//     vmcnt(0) at every barrier, serializing the stream -> 2x slowdown).
//   Phase C: folded into last chunk tail.
// ---------------------------------------------------------------------------

using half_t  = _Float16;
using half2_t = __attribute__((ext_vector_type(2))) _Float16;
using half8_t = __attribute__((ext_vector_type(8))) _Float16;
using f32x4   = __attribute__((ext_vector_type(4))) float;

#define L_SEQ   2048
#define CHUNK_L 1024
#define NB      64
#define DIM     256
#define P4      1024                 // 4 gates * H
#define CM      (CHUNK_L * NB)       // 65536 rows per chunk

// workspace layout (bytes)
#define OFF_GATES 0ull
#define SZ_GATES  ((unsigned long long)CM * P4 * 2)        // 134217728
#define OFF_EMBH  (OFF_GATES + SZ_GATES)
#define SZ_EMBH   (50257ull * 256 * 2)                     // 25731584
#define OFF_WX    (OFF_EMBH + SZ_EMBH)
#define SZ_WX     (1024ull * 256 * 2)
#define OFF_WH    (OFF_WX + SZ_WX)
#define SZ_WH     (1024ull * 256 * 2)
#define OFF_B4    (OFF_WH + SZ_WH)
#define SZ_B4     (1024ull * 4)
#define OFF_ST    (OFF_B4 + SZ_B4)
#define SZ_ST     (2ull * NB * DIM * 4)                    // h,c f32 state
#define WS_NEED   (OFF_ST + SZ_ST)                         // ~161.1 MB

// ---------------- helpers ----------------
__device__ __forceinline__ float sigm(float x) {
  x = fminf(fmaxf(x, -30.f), 30.f);
  return 1.f / (1.f + __expf(-x));
}
__device__ __forceinline__ float tanh_(float x) {
  x = fminf(fmaxf(x, -15.f), 15.f);
  float t = __expf(2.f * x);
  return (t - 1.f) / (t + 1.f);
}
__device__ __forceinline__ float dot8(half8_t w, half8_t h, float acc) {
  acc = __builtin_amdgcn_fdot2((half2_t)__builtin_shufflevector(w, w, 0, 1),
                               (half2_t)__builtin_shufflevector(h, h, 0, 1), acc, false);
  acc = __builtin_amdgcn_fdot2((half2_t)__builtin_shufflevector(w, w, 2, 3),
                               (half2_t)__builtin_shufflevector(h, h, 2, 3), acc, false);
  acc = __builtin_amdgcn_fdot2((half2_t)__builtin_shufflevector(w, w, 4, 5),
                               (half2_t)__builtin_shufflevector(h, h, 4, 5), acc, false);
  acc = __builtin_amdgcn_fdot2((half2_t)__builtin_shufflevector(w, w, 6, 7),
                               (half2_t)__builtin_shufflevector(h, h, 6, 7), acc, false);
  return acc;
}

// LDS-only barrier, NO memory clobber -> vmcnt untouched, stream loads
// stay in flight (m201 template pattern; rule #18 sched_barrier fences).
#define SBAR() do {                                   \
    __builtin_amdgcn_sched_barrier(0);                \
    asm volatile("s_waitcnt lgkmcnt(0)" ::);          \
    __builtin_amdgcn_s_barrier();                     \
    __builtin_amdgcn_sched_barrier(0);                \
  } while (0)

// ---------------- kernels ----------------
__global__ void ws_too_small_kernel(float* out, float sz) {
  if (threadIdx.x == 0 && blockIdx.x == 0) out[0] = sz;
}

__global__ void cvt_emb_kernel(const float* __restrict__ src, half_t* __restrict__ dst,
                               int total8) {
  int i = blockIdx.x * blockDim.x + threadIdx.x;
  if (i >= total8) return;
  const float4* s = (const float4*)src + (size_t)i * 2;
  float4 a = s[0], b = s[1];
  half8_t o;
  o[0] = (half_t)a.x; o[1] = (half_t)a.y; o[2] = (half_t)a.z; o[3] = (half_t)a.w;
  o[4] = (half_t)b.x; o[5] = (half_t)b.y; o[6] = (half_t)b.z; o[7] = (half_t)b.w;
  *((half8_t*)dst + i) = o;
}

// Wx4h[p][k] row-major fp16; Wh4c[(k>>3)][p][k&7] (16B chunk per (kc,p));
// b4 = bx + bh
__global__ void pack_w_kernel(const float* __restrict__ Wii, const float* __restrict__ Whi,
                              const float* __restrict__ Wif, const float* __restrict__ Whf,
                              const float* __restrict__ Wig, const float* __restrict__ Whg,
                              const float* __restrict__ Wio, const float* __restrict__ Who,
                              const float* __restrict__ bii, const float* __restrict__ bhi,
                              const float* __restrict__ bif, const float* __restrict__ bhf,
                              const float* __restrict__ big_, const float* __restrict__ bhg,
                              const float* __restrict__ bio, const float* __restrict__ bho,
                              half_t* __restrict__ Wx4h, half_t* __restrict__ Wh4c,
                              float* __restrict__ b4) {
  int p = blockIdx.x;   // 0..1023
  int k = threadIdx.x;  // 0..255
  int g = p >> 8, h = p & 255;
  const float* Wx = g == 0 ? Wii : g == 1 ? Wif : g == 2 ? Wig : Wio;
  const float* Wh = g == 0 ? Whi : g == 1 ? Whf : g == 2 ? Whg : Who;
  Wx4h[(size_t)p * DIM + k] = (half_t)Wx[h * DIM + k];
  Wh4c[((size_t)(k >> 3) * P4 + p) * 8 + (k & 7)] = (half_t)Wh[h * DIM + k];
  if (k == 0) {
    const float* bx = g == 0 ? bii : g == 1 ? bif : g == 2 ? big_ : bio;
    const float* bh = g == 0 ? bhi : g == 1 ? bhf : g == 2 ? bhg : bho;
    b4[p] = bx[h] + bh[h];
  }
}

// Phase A GEMM (unchanged; 128x128 tile, mfma_f32_16x16x32_f16)
#define BK   32
#define LSTR 40
__global__ __launch_bounds__(256) void gemm_gates_kernel(
    const half_t* __restrict__ embh, const int* __restrict__ xc,
    const half_t* __restrict__ Wx4h, const float* __restrict__ b4,
    half_t* __restrict__ gates) {
  __shared__ __align__(16) half_t As[128 * LSTR];
  __shared__ __align__(16) half_t Ws[128 * LSTR];
  const int tid  = threadIdx.x;
  const int lane = tid & 63;
  const int wave = tid >> 6;
  const int wm = wave >> 1, wn = wave & 1;
  const int M0 = blockIdx.x * 128;
  const int P0 = blockIdx.y * 128;
  const int r0 = tid >> 2, s0 = tid & 3;

  const size_t arow0 = (size_t)xc[M0 + r0] * DIM;
  const size_t arow1 = (size_t)xc[M0 + 64 + r0] * DIM;
  const size_t wrow0 = (size_t)(P0 + r0) * DIM;
  const size_t wrow1 = (size_t)(P0 + 64 + r0) * DIM;

  f32x4 acc[4][4] = {};
  const int fr = lane & 15;
  const int kq = lane >> 4;

  for (int kt = 0; kt < 8; ++kt) {
    const int k0 = kt * BK;
    half8_t a0 = *(const half8_t*)(embh + arow0 + k0 + s0 * 8);
    half8_t a1 = *(const half8_t*)(embh + arow1 + k0 + s0 * 8);
    half8_t w0 = *(const half8_t*)(Wx4h + wrow0 + k0 + s0 * 8);
    half8_t w1 = *(const half8_t*)(Wx4h + wrow1 + k0 + s0 * 8);
    __syncthreads();
    *(half8_t*)(As + r0 * LSTR + s0 * 8)        = a0;
    *(half8_t*)(As + (r0 + 64) * LSTR + s0 * 8) = a1;
    *(half8_t*)(Ws + r0 * LSTR + s0 * 8)        = w0;
    *(half8_t*)(Ws + (r0 + 64) * LSTR + s0 * 8) = w1;
    __syncthreads();
    half8_t af[4], bf[4];
#pragma unroll
    for (int mi = 0; mi < 4; ++mi)
      af[mi] = *(const half8_t*)(As + (wm * 64 + mi * 16 + fr) * LSTR + kq * 8);
#pragma unroll
    for (int ni = 0; ni < 4; ++ni)
      bf[ni] = *(const half8_t*)(Ws + (wn * 64 + ni * 16 + fr) * LSTR + kq * 8);
#pragma unroll
    for (int mi = 0; mi < 4; ++mi)
#pragma unroll
      for (int ni = 0; ni < 4; ++ni)
        acc[mi][ni] = __builtin_amdgcn_mfma_f32_16x16x32_f16(af[mi], bf[ni], acc[mi][ni], 0, 0, 0);
  }
  const int rbase = (lane >> 4) * 4;
#pragma unroll
  for (int ni = 0; ni < 4; ++ni) {
    const int p = P0 + wn * 64 + ni * 16 + fr;
    const float bias = b4[p];
#pragma unroll
    for (int mi = 0; mi < 4; ++mi) {
      const int m = M0 + wm * 64 + mi * 16 + rbase;
#pragma unroll
      for (int r = 0; r < 4; ++r)
        gates[(size_t)(m + r) * P4 + p] = (half_t)(acc[mi][ni][r] + bias);
    }
  }
}

// ---- resident tier (kcRel 0..3, 4 gate rows): 16 half8 = 64 VGPRs ----
#define DECLR(r) half8_t R##r##_0, R##r##_1, R##r##_2, R##r##_3;
#define LOADR(r)                                   \
  R##r##_0 = W8[(kcb + (r)) * P4 + p0];            \
  R##r##_1 = W8[(kcb + (r)) * P4 + p1];            \
  R##r##_2 = W8[(kcb + (r)) * P4 + p2];            \
  R##r##_3 = W8[(kcb + (r)) * P4 + p3];
#define PINR(r)                                                             \
  asm volatile("" : "+v"(R##r##_0), "+v"(R##r##_1), "+v"(R##r##_2),         \
                    "+v"(R##r##_3));
#define RGRP(r) { const half8_t hh = hp[r];        \
  a0 = dot8(R##r##_0, hh, a0); a1 = dot8(R##r##_1, hh, a1);                 \
  a2 = dot8(R##r##_2, hh, a2); a3 = dot8(R##r##_3, hh, a3); }

// ---- LDS tier (kcRel 4..7): slot = kh*4 + (r-4) ----
#define LGRP(r) { const half8_t hh = hp[r]; const int sl = (kh << 2) + (r) - 4; \
  a0 = dot8(*(const half8_t*)wlds[sl][p0], hh, a0);                         \
  a1 = dot8(*(const half8_t*)wlds[sl][p1], hh, a1);                         \
  a2 = dot8(*(const half8_t*)wlds[sl][p2], hh, a2);                         \
  a3 = dot8(*(const half8_t*)wlds[sl][p3], hh, a3); }

// ---- stream tier (kcRel 8..15): consume slot, reissue for kcRel rn ----
#define SGRP(r, sa, sb, sc, sd, rn) { const half8_t hh = hp[r];             \
  a0 = dot8(sa, hh, a0); sa = W8[(kcb + (rn)) * P4 + p0];                   \
  a1 = dot8(sb, hh, a1); sb = W8[(kcb + (rn)) * P4 + p1];                   \
  a2 = dot8(sc, hh, a2); sc = W8[(kcb + (rn)) * P4 + p2];                   \
  a3 = dot8(sd, hh, a3); sd = W8[(kcb + (rn)) * P4 + p3]; }

// Phase B: 64 blocks (1 chain each), 512 threads, thread = (j, kh).
__global__ __launch_bounds__(512)
void lstm_kernel(const half_t* __restrict__ gates, const half_t* __restrict__ Wh4c,
                 const float* __restrict__ Wout, const float* __restrict__ bout,
                 float* __restrict__ out, float* __restrict__ state,
                 int first, int last) {
  const int n   = blockIdx.x;
  const int tid = threadIdx.x;
  const int j   = tid & 255;
  const int kh  = tid >> 8;
  __shared__ __align__(16) half_t wlds[8][P4][8];   // 128 KB: abs kc {4-7,20-23}
  __shared__ __align__(16) half_t hbuf[2][DIM];     // 1 KB
  __shared__ __align__(16) float  partial4[DIM][4]; // 4 KB
  __shared__ float hfin[DIM];

  const half8_t* W8 = (const half8_t*)Wh4c;
  // LDS weight cache fill: slot s -> abs kc = (s>>2)*16 + 4 + (s&3)
  for (int i = tid; i < 8192; i += 512) {
    const int s = i >> 10, pp = i & 1023;
    const int kc = ((s >> 2) << 4) + 4 + (s & 3);
    *(half8_t*)wlds[s][pp] = W8[kc * P4 + pp];
  }
  const int kcb = kh << 4;
  const int p0 = j, p1 = 256 + j, p2 = 512 + j, p3 = 768 + j;

  DECLR(0) DECLR(1) DECLR(2) DECLR(3)
  LOADR(0) LOADR(1) LOADR(2) LOADR(3)
  PINR(0) PINR(1) PINR(2) PINR(3)
  // ring prime: S0-3 = kcRel 8 rows 0-3; S4-7 = kcRel 9 rows 0-3
  half8_t S0 = W8[(kcb + 8) * P4 + p0], S1 = W8[(kcb + 8) * P4 + p1];
  half8_t S2 = W8[(kcb + 8) * P4 + p2], S3 = W8[(kcb + 8) * P4 + p3];
  half8_t S4 = W8[(kcb + 9) * P4 + p0], S5 = W8[(kcb + 9) * P4 + p1];
  half8_t S6 = W8[(kcb + 9) * P4 + p2], S7 = W8[(kcb + 9) * P4 + p3];

  float cc = 0.f, hkeep = 0.f;
  if (kh == 0) {
    float h0 = 0.f;
    if (!first) { h0 = state[n * DIM + j]; cc = state[NB * DIM + n * DIM + j]; }
    hbuf[0][j] = (half_t)h0;
    hkeep = h0;
  }
  const half_t* gbase = gates + (size_t)n * P4;
  float g0f = 0.f, g1f = 0.f, g2f = 0.f, g3f = 0.f;
  if (kh == 1) {
    g0f = (float)gbase[p0]; g1f = (float)gbase[p1];
    g2f = (float)gbase[p2]; g3f = (float)gbase[p3];
  }
  __syncthreads();

#pragma unroll 1
  for (int l = 0; l < CHUNK_L; ++l) {
    float a0 = 0.f, a1 = 0.f, a2 = 0.f, a3 = 0.f;
    half_t ng0 = (half_t)0.f, ng1 = ng0, ng2 = ng0, ng3 = ng0;
    if (kh == 1) {
      a0 = g0f; a1 = g1f; a2 = g2f; a3 = g3f;
      // issue next-step gate loads FIRST (so later vmcnt waits for them
      // never force the ring to drain); last-iter read lands in embh: ok
      const half_t* gp2 = gbase + (size_t)(l + 1) * (NB * P4);
      ng0 = gp2[p0]; ng1 = gp2[p1]; ng2 = gp2[p2]; ng3 = gp2[p3];
    }
    const half8_t* hp = (const half8_t*)hbuf[l & 1] + kcb;
    // stream groups interleaved with LDS/resident so each slot's reissue
    // has ~12 dot8 (~250+ cyc) before its next consume
    SGRP(8,  S0, S1, S2, S3, 10) LGRP(4)
    SGRP(9,  S4, S5, S6, S7, 11) LGRP(5)
    SGRP(10, S0, S1, S2, S3, 12) LGRP(6)
    SGRP(11, S4, S5, S6, S7, 13) LGRP(7)
    SGRP(12, S0, S1, S2, S3, 14) RGRP(0)
    SGRP(13, S4, S5, S6, S7, 15) RGRP(1)
    SGRP(14, S0, S1, S2, S3, 8)  RGRP(2)   // wrap: reload for next step
    SGRP(15, S4, S5, S6, S7, 9)  RGRP(3)
    if (kh == 1) {
      float4 pv; pv.x = a0; pv.y = a1; pv.z = a2; pv.w = a3;
      *(float4*)partial4[j] = pv;
    }
    SBAR();                      // LDS drain only; stream stays in flight
    if (kh == 0) {
      float4 pv = *(const float4*)partial4[j];
      a0 += pv.x; a1 += pv.y; a2 += pv.z; a3 += pv.w;
      const float it = sigm(a0), ft = sigm(a1), gt = tanh_(a2), ot = sigm(a3);
      cc = ft * cc + it * gt;
      const float h = ot * tanh_(cc);
      hbuf[(l + 1) & 1][j] = (half_t)h;
      hkeep = h;
    }
    SBAR();
    if (kh == 1) {               // gates from the loads issued at step top
      g0f = (float)ng0; g1f = (float)ng1; g2f = (float)ng2; g3f = (float)ng3;
    }
  }
  __syncthreads();
  // CHUNK_L even -> final h in hbuf[0] (hkeep on kh==0)
  if (kh == 0) {
    if (!last) { state[n * DIM + j] = hkeep; state[NB * DIM + n * DIM + j] = cc; }
    hfin[j] = hkeep;
  }
  __syncthreads();
  if (last && tid < 10) {
    float s = bout[tid];
    const float* wrow = Wout + tid * DIM;
#pragma unroll 4
    for (int k = 0; k < DIM; ++k) s += hfin[k] * wrow[k];
    out[n * 10 + tid] = s;
  }
}

// ---------------- launch ----------------
extern "C" void kernel_launch(void* const* d_in, const int* in_sizes, int n_in,
                              void* d_out, int out_size, void* d_ws, size_t ws_size,
                              hipStream_t stream) {
  const int*   x    = (const int*)d_in[0];
  const float* emb  = (const float*)d_in[1];
  const float* Wii  = (const float*)d_in[2];  const float* bii = (const float*)d_in[3];
  const float* Whi  = (const float*)d_in[4];  const float* bhi = (const float*)d_in[5];
  const float* Wif  = (const float*)d_in[6];  const float* bif = (const float*)d_in[7];
  const float* Whf  = (const float*)d_in[8];  const float* bhf = (const float*)d_in[9];
  const float* Wig  = (const float*)d_in[10]; const float* big_ = (const float*)d_in[11];
  const float* Whg  = (const float*)d_in[12]; const float* bhg = (const float*)d_in[13];
  const float* Wio  = (const float*)d_in[14]; const float* bio = (const float*)d_in[15];
  const float* Who  = (const float*)d_in[16]; const float* bho = (const float*)d_in[17];
  const float* Wout = (const float*)d_in[18]; const float* bout = (const float*)d_in[19];
  float* out = (float*)d_out;

  if (ws_size < WS_NEED) {  // fail loudly but safely: absmax will show ws_size
    hipLaunchKernelGGL(ws_too_small_kernel, dim3(1), dim3(64), 0, stream, out, (float)ws_size);
    return;
  }
  char* ws = (char*)d_ws;
  half_t* gates = (half_t*)(ws + OFF_GATES);
  half_t* embh  = (half_t*)(ws + OFF_EMBH);
  half_t* Wx4h  = (half_t*)(ws + OFF_WX);
  half_t* Wh4c  = (half_t*)(ws + OFF_WH);
  float*  b4    = (float*)(ws + OFF_B4);
  float*  state = (float*)(ws + OFF_ST);

  const int total8 = 50257 * 32;  // V*D/8
  hipLaunchKernelGGL(cvt_emb_kernel, dim3((total8 + 255) / 256), dim3(256), 0, stream,
                     emb, embh, total8);
  hipLaunchKernelGGL(pack_w_kernel, dim3(1024), dim3(256), 0, stream,
                     Wii, Whi, Wif, Whf, Wig, Whg, Wio, Who,
                     bii, bhi, bif, bhf, big_, bhg, bio, bho,
                     Wx4h, Wh4c, b4);
  // chunk 0: steps [0, 1024)
  hipLaunchKernelGGL(gemm_gates_kernel, dim3(CM / 128, P4 / 128), dim3(256), 0, stream,
                     embh, x, Wx4h, b4, gates);
  hipLaunchKernelGGL(lstm_kernel, dim3(NB), dim3(512), 0, stream,
                     gates, Wh4c, Wout, bout, out, state, 1, 0);
  // chunk 1: steps [1024, 2048)
  hipLaunchKernelGGL(gemm_gates_kernel, dim3(CM / 128, P4 / 128), dim3(256), 0, stream,
                     embh, x + (size_t)CHUNK_L * NB, Wx4h, b4, gates);
  hipLaunchKernelGGL(lstm_kernel, dim3(NB), dim3(512), 0, stream,
                     gates, Wh4c, Wout, bout, out, state, 0, 1);
}